// Round 9
// baseline (1657.318 us; speedup 1.0000x reference)
//
#include <hip/hip_runtime.h>
#include <hip/hip_fp16.h>

typedef _Float16 f16;
typedef _Float16 f16x8 __attribute__((ext_vector_type(8)));
typedef __fp16 fp16x2_raw __attribute__((ext_vector_type(2)));
typedef float f32x4 __attribute__((ext_vector_type(4)));

#define DD 512
#define BM 8      // entities per block
#define WW 6
#define NH 8
#define EP 520    // padded LDS row stride (f16 elems): 260 dw -> rows +4 banks, <=2-way conflicts

union F16x8 { f16x8 v; unsigned u[4]; uint2 u2[2]; };
union H2U { __half2 h; unsigned u; };
union U4H { uint4 q; __half2 h[4]; };

__device__ __forceinline__ unsigned pkrtz(float a, float b) {
  union { fp16x2_raw h; unsigned u; } c;
  c.h = __builtin_amdgcn_cvt_pkrtz(a, b);
  return c.u;
}
__device__ __forceinline__ unsigned short f2h(float x) {
  union { f16 h; unsigned short u; } c; c.h = (f16)x; return c.u;
}
#define SCHED_FENCE() __builtin_amdgcn_sched_barrier(0)

// ---------- prep: transpose float[R][C] -> f16[C][R] ----------
__global__ void k_tr_f16(const float* __restrict__ src, unsigned short* __restrict__ dst,
                         int R, int C) {
  __shared__ float tile[64][65];
  int tpc = C >> 6;
  int tr = (blockIdx.x / tpc) << 6;
  int tc = (blockIdx.x % tpc) << 6;
  int t = threadIdx.x;
  #pragma unroll
  for (int i = 0; i < 16; ++i) {
    int idx = i * 256 + t; int r = idx >> 6, c = idx & 63;
    tile[r][c] = src[(size_t)(tr + r) * C + tc + c];
  }
  __syncthreads();
  #pragma unroll
  for (int i = 0; i < 16; ++i) {
    int idx = i * 256 + t; int c = idx >> 6, r = idx & 63;
    dst[(size_t)(tc + c) * R + tr + r] = f2h(tile[r][c]);
  }
}

// ---------- prep: plain convert float -> f16 ----------
__global__ void k_cvt4_f16(const float* __restrict__ src, unsigned short* __restrict__ dst, int n4) {
  int i = blockIdx.x * blockDim.x + threadIdx.x;
  if (i < n4) {
    float4 v = ((const float4*)src)[i];
    ushort4 o; o.x = f2h(v.x); o.y = f2h(v.y); o.z = f2h(v.z); o.w = f2h(v.w);
    ((ushort4*)dst)[i] = o;
  }
}

// ---------- main fused kernel: 8 entities/block, 8 waves = 8 heads, f16, pad-520 LDS ----------
// launch_bounds 2nd arg = min BLOCKS/CU (CUDA semantics, r3) -> 128 total-reg cap, 2 blocks/CU.
// r7 lesson: VALU fat was addressing (XOR swizzle) + f2bf + scr LDS round-trip. This version:
// pad-520 rows (offset-immediate addressing), f16 + cvt_pkrtz + hfma2, double operand-swap
// (Q^T and Qk^T in regs, k-slot permutation shared by A and B frags) -> no scratch LDS.
__global__ __launch_bounds__(512, 2) void trust_main(
    const float* __restrict__ h_i, const float* __restrict__ evo,
    const float* __restrict__ var_i, const float* __restrict__ var_j,
    const float* __restrict__ bq, const float* __restrict__ bk, const float* __restrict__ bv,
    const float* __restrict__ ld, const float* __restrict__ b1,
    const float* __restrict__ W2, const float* __restrict__ b2,
    const unsigned short* __restrict__ wqT, const unsigned short* __restrict__ wkB,
    const unsigned short* __restrict__ wvT, const unsigned short* __restrict__ w1T,
    float* __restrict__ out) {
  __shared__ unsigned short evo_s[48 * EP];   // 49920 B f16, rows L = e*6+w
  __shared__ unsigned short qh_s[16 * EP];    // 16640 B f16, h (rows 0-7) -> pooled (rows 0-15)
  __shared__ float score_s[NH * BM * WW];     // 1536 B
  __shared__ float logit_s[16 * NH];          // 512 B
  __shared__ float conf_s[BM];                // 32 B
  // total ~68.6 KB -> 2 blocks/CU

  const int t = threadIdx.x;
  const int wv = t >> 6;       // wave == head
  const int l = t & 63;
  const int l16 = l & 15;
  const int lq = l >> 4;
  const int e0 = blockIdx.x * BM;

  // decay bias
  float biasw[WW];
  {
    float rd = expf(ld[0]);
    float dsum = 0.f;
    #pragma unroll
    for (int w6 = 0; w6 < WW; ++w6) { biasw[w6] = expf(rd * (float)w6); dsum += biasw[w6]; }
    float dinv = 1.f / dsum;
    #pragma unroll
    for (int w6 = 0; w6 < WW; ++w6) biasw[w6] *= dinv;
  }

  // ---- P0: stage evo + h to LDS as f16 (padded rows); zero h rows 8-15; conf ----
  {
    const float4* ev4 = (const float4*)evo + (size_t)e0 * (WW * DD / 4);
    #pragma unroll
    for (int i = 0; i < 12; ++i) {
      int idx = i * 512 + t;
      int row = idx >> 7, c4 = idx & 127;
      float4 v = ev4[idx];
      uint2 o; o.x = pkrtz(v.x, v.y); o.y = pkrtz(v.z, v.w);
      *(uint2*)&evo_s[row * EP + c4 * 4] = o;
    }
    const float4* h4 = (const float4*)h_i + (size_t)e0 * (DD / 4);
    #pragma unroll
    for (int i = 0; i < 2; ++i) {
      int idx = i * 512 + t;
      int row = idx >> 7, c4 = idx & 127;
      float4 v = h4[idx];
      uint2 o; o.x = pkrtz(v.x, v.y); o.y = pkrtz(v.z, v.w);
      *(uint2*)&qh_s[row * EP + c4 * 4] = o;
    }
    #pragma unroll
    for (int i = 0; i < 2; ++i) {   // zero rows 8-15 (keeps lanes 8-15 garbage-free)
      int idx = i * 512 + t;
      int row = 8 + (idx >> 7), c4 = idx & 127;
      uint2 z; z.x = 0; z.y = 0;
      *(uint2*)&qh_s[row * EP + c4 * 4] = z;
    }
    const float4* vi4 = (const float4*)var_i + (size_t)(e0 + wv) * (DD / 4);
    const float4* vj4 = (const float4*)var_j + (size_t)(e0 + wv) * (DD / 4);
    float si = 0.f, sj = 0.f;
    #pragma unroll
    for (int i = 0; i < 2; ++i) {
      float4 a = vi4[l * 2 + i]; si += a.x + a.y + a.z + a.w;
      float4 b = vj4[l * 2 + i]; sj += b.x + b.y + b.z + b.w;
    }
    #pragma unroll
    for (int m = 1; m <= 32; m <<= 1) { si += __shfl_xor(si, m); sj += __shfl_xor(sj, m); }
    if (l == 0) {
      float ci = 1.f / (1.f + fmaxf(sqrtf(si * (1.f / DD)), 1e-6f));
      float cj = 1.f / (1.f + fmaxf(sqrtf(sj * (1.f / DD)), 1e-6f));
      conf_s[wv] = fmaxf(0.5f * (logf(ci) + logf(cj)), -5.0f);
    }
  }
  __syncthreads();   // B1
  SCHED_FENCE();

  // ---- P1: Q^T = Wq_head^T @ h^T -> lane l16 = entity, rows = head-col; Q stays in regs ----
  F16x8 qfr[2];      // qk B-frags (k = head dim, pi-slot order)
  float qb;          // Q[e].bk_head at lane l16=e
  {
    f32x4 qacc[4] = {};
    const unsigned short* wqp = wqT + (size_t)(wv * 64 + l16) * DD + lq * 8;
    #pragma unroll 2
    for (int kst = 0; kst < 16; ++kst) {
      f16x8 hb = *reinterpret_cast<const f16x8*>(&qh_s[l16 * EP + kst * 32 + lq * 8]);
      #pragma unroll
      for (int ct = 0; ct < 4; ++ct) {
        f16x8 a = *reinterpret_cast<const f16x8*>(&wqp[ct * 16 * DD + kst * 32]);
        qacc[ct] = __builtin_amdgcn_mfma_f32_16x16x32_f16(a, hb, qacc[ct], 0, 0, 0);
      }
    }
    __syncthreads();   // B2: all waves done reading h (qh rows reused by pooled later)
    qb = 0.f;
    #pragma unroll
    for (int ct = 0; ct < 4; ++ct) {
      float4 bq4 = *(const float4*)&bq[wv * 64 + ct * 16 + lq * 4];
      float4 bk4 = *(const float4*)&bk[wv * 64 + ct * 16 + lq * 4];
      float q0 = qacc[ct][0] + bq4.x, q1 = qacc[ct][1] + bq4.y;
      float q2 = qacc[ct][2] + bq4.z, q3 = qacc[ct][3] + bq4.w;
      qb += q0 * bk4.x + q1 * bk4.y + q2 * bk4.z + q3 * bk4.w;
      qfr[ct >> 1].u[(ct & 1) * 2]     = pkrtz(q0, q1);
      qfr[ct >> 1].u[(ct & 1) * 2 + 1] = pkrtz(q2, q3);
    }
    qb += __shfl_xor(qb, 16);
    qb += __shfl_xor(qb, 32);   // lane l16=e now holds qb[e]
  }
  SCHED_FENCE();

  // ---- score: Qk^T chunk (regs) -> A-frag via cvt_pkrtz (pi order) -> 3 evo MFMAs ----
  f32x4 sacc0 = {}, sacc1 = {}, sacc2 = {};
  {
    const unsigned short* wkp = wkB + (size_t)l16 * DD + wv * 64 + lq * 4;
    #pragma unroll 2
    for (int ch = 0; ch < 16; ++ch) {
      f32x4 qk0 = {}, qk1 = {};
      #pragma unroll
      for (int kst = 0; kst < 2; ++kst) {
        const unsigned short* p = wkp + ch * 32 * DD + kst * 32;
        F16x8 a0, a1;
        a0.u2[0] = *(const uint2*)(p);
        a0.u2[1] = *(const uint2*)(p + 16);
        a1.u2[0] = *(const uint2*)(p + 16 * DD);
        a1.u2[1] = *(const uint2*)(p + 16 * DD + 16);
        qk0 = __builtin_amdgcn_mfma_f32_16x16x32_f16(a0.v, qfr[kst].v, qk0, 0, 0, 0);
        qk1 = __builtin_amdgcn_mfma_f32_16x16x32_f16(a1.v, qfr[kst].v, qk1, 0, 0, 0);
      }
      F16x8 af;
      af.u[0] = pkrtz(qk0[0], qk0[1]); af.u[1] = pkrtz(qk0[2], qk0[3]);
      af.u[2] = pkrtz(qk1[0], qk1[1]); af.u[3] = pkrtz(qk1[2], qk1[3]);
      int cb = ch * 32 + lq * 4;
      {
        F16x8 b; b.u2[0] = *(const uint2*)&evo_s[l16 * EP + cb];
        b.u2[1] = *(const uint2*)&evo_s[l16 * EP + cb + 16];
        sacc0 = __builtin_amdgcn_mfma_f32_16x16x32_f16(af.v, b.v, sacc0, 0, 0, 0);
      }
      {
        F16x8 b; b.u2[0] = *(const uint2*)&evo_s[(16 + l16) * EP + cb];
        b.u2[1] = *(const uint2*)&evo_s[(16 + l16) * EP + cb + 16];
        sacc1 = __builtin_amdgcn_mfma_f32_16x16x32_f16(af.v, b.v, sacc1, 0, 0, 0);
      }
      {
        F16x8 b; b.u2[0] = *(const uint2*)&evo_s[(32 + l16) * EP + cb];
        b.u2[1] = *(const uint2*)&evo_s[(32 + l16) * EP + cb + 16];
        sacc2 = __builtin_amdgcn_mfma_f32_16x16x32_f16(af.v, b.v, sacc2, 0, 0, 0);
      }
    }
  }
  SCHED_FENCE();

  // extract S[e][w] (score D: lane=L col, rows=e; L=6e+w<=47 => e<=7 automatic)
  #pragma unroll
  for (int r = 0; r < 4; ++r) {
    int e = lq * 4 + r;
    { int w = l16 - 6 * e;      if (w >= 0 && w < WW) score_s[wv * 48 + e * 6 + w] = sacc0[r]; }
    { int w = 16 + l16 - 6 * e; if (w >= 0 && w < WW) score_s[wv * 48 + e * 6 + w] = sacc1[r]; }
    { int w = 32 + l16 - 6 * e; if (w >= 0 && w < WW) score_s[wv * 48 + e * 6 + w] = sacc2[r]; }
  }
  // softmax (per-wave slice, same-wave LDS ordering)
  #pragma unroll
  for (int r = 0; r < 4; ++r) {
    int e = lq * 4 + r;
    if (e < BM) {
      float qbv = __shfl(qb, e);
      float sc[WW]; float mx = -1e30f;
      #pragma unroll
      for (int w6 = 0; w6 < WW; ++w6) {
        sc[w6] = 0.125f * (score_s[wv * 48 + e * 6 + w6] + qbv) + biasw[w6];
        mx = fmaxf(mx, sc[w6]);
      }
      float ssum = 0.f;
      #pragma unroll
      for (int w6 = 0; w6 < WW; ++w6) { sc[w6] = expf(sc[w6] - mx); ssum += sc[w6]; }
      float sinv = 1.f / ssum;
      if (l16 == 0) {
        #pragma unroll
        for (int w6 = 0; w6 < WW; ++w6) score_s[wv * 48 + e * 6 + w6] = sc[w6] * sinv;
      }
    }
  }
  SCHED_FENCE();

  // ---- agg via hfma2 (lane = entity l16&7) -> A-frag direct; pooled MFMA vs WvT ----
  f32x4 pacc[4] = {};
  {
    __half2 aw2[WW];
    #pragma unroll
    for (int w6 = 0; w6 < WW; ++w6) {
      float v = score_s[wv * 48 + (l16 & 7) * 6 + w6];
      H2U a; a.u = pkrtz(v, v); aw2[w6] = a.h;
    }
    const unsigned short* wvp = wvT + (size_t)(wv * 64 + l16) * DD + lq * 8;
    const int arow = (l16 & 7) * 6;
    #pragma unroll 2
    for (int ch = 0; ch < 16; ++ch) {
      H2U z; z.u = 0;
      __half2 ac0 = z.h, ac1 = z.h, ac2 = z.h, ac3 = z.h;
      #pragma unroll
      for (int w6 = 0; w6 < WW; ++w6) {
        U4H vv; vv.q = *(const uint4*)&evo_s[(arow + w6) * EP + ch * 32 + lq * 8];
        ac0 = __hfma2(vv.h[0], aw2[w6], ac0);
        ac1 = __hfma2(vv.h[1], aw2[w6], ac1);
        ac2 = __hfma2(vv.h[2], aw2[w6], ac2);
        ac3 = __hfma2(vv.h[3], aw2[w6], ac3);
      }
      F16x8 af;
      { H2U c; c.h = ac0; af.u[0] = c.u; c.h = ac1; af.u[1] = c.u;
        c.h = ac2; af.u[2] = c.u; c.h = ac3; af.u[3] = c.u; }
      #pragma unroll
      for (int ct = 0; ct < 4; ++ct) {
        f16x8 b = *reinterpret_cast<const f16x8*>(&wvp[ct * 16 * DD + ch * 32]);
        pacc[ct] = __builtin_amdgcn_mfma_f32_16x16x32_f16(af.v, b, pacc[ct], 0, 0, 0);
      }
    }
  }
  SCHED_FENCE();

  // pooled -> qh_s rows e (f16); lane = dv col
  #pragma unroll
  for (int ct = 0; ct < 4; ++ct) {
    int col = wv * 64 + ct * 16 + l16;
    float bvv = bv[col];
    #pragma unroll
    for (int r = 0; r < 4; ++r)
      qh_s[(lq * 4 + r) * EP + col] = f2h(pacc[ct][r] + bvv);
  }
  __syncthreads();   // B3

  // ---- P6: hmid = gelu(pooled @ W1 + b1); logit partials ----
  {
    f32x4 hacc[2] = {};
    const unsigned short* w1p = w1T + (size_t)(wv * 32 + l16) * DD + lq * 8;
    #pragma unroll 4
    for (int kst = 0; kst < 16; ++kst) {
      f16x8 a = *reinterpret_cast<const f16x8*>(&qh_s[l16 * EP + kst * 32 + lq * 8]);
      #pragma unroll
      for (int ct = 0; ct < 2; ++ct) {
        f16x8 b = *reinterpret_cast<const f16x8*>(&w1p[ct * 16 * DD + kst * 32]);
        hacc[ct] = __builtin_amdgcn_mfma_f32_16x16x32_f16(a, b, hacc[ct], 0, 0, 0);
      }
    }
    float lg[4] = {0.f, 0.f, 0.f, 0.f};
    #pragma unroll
    for (int ct = 0; ct < 2; ++ct) {
      int m = wv * 32 + ct * 16 + l16;
      float b1v = b1[m], w2v = W2[m];
      #pragma unroll
      for (int r = 0; r < 4; ++r) {
        float x = hacc[ct][r] + b1v;
        float g = 0.5f * x * (1.f + erff(x * 0.70710678118f));
        lg[r] += g * w2v;
      }
    }
    #pragma unroll
    for (int r = 0; r < 4; ++r) {
      #pragma unroll
      for (int m = 1; m <= 8; m <<= 1) lg[r] += __shfl_xor(lg[r], m);
    }
    if (l16 == 0) {
      #pragma unroll
      for (int r = 0; r < 4; ++r) logit_s[(lq * 4 + r) * NH + wv] = lg[r];
    }
  }
  __syncthreads();   // B4

  // ---- P7: combine + sigmoid ----
  if (t < BM) {
    float s = 0.f;
    #pragma unroll
    for (int w8 = 0; w8 < NH; ++w8) s += logit_s[t * NH + w8];
    s += b2[0] + conf_s[t];
    out[e0 + t] = 1.f / (1.f + expf(-s));
  }
}

extern "C" void kernel_launch(void* const* d_in, const int* in_sizes, int n_in,
                              void* d_out, int out_size, void* d_ws, size_t ws_size,
                              hipStream_t stream) {
  (void)in_sizes; (void)n_in; (void)out_size; (void)ws_size;
  const float* h_i = (const float*)d_in[0];
  const float* evo = (const float*)d_in[1];
  const float* vi  = (const float*)d_in[2];
  const float* vj  = (const float*)d_in[3];
  const float* Wq  = (const float*)d_in[4];
  const float* bq  = (const float*)d_in[5];
  const float* Wk  = (const float*)d_in[6];
  const float* bk  = (const float*)d_in[7];
  const float* Wv  = (const float*)d_in[8];
  const float* bv  = (const float*)d_in[9];
  const float* ld  = (const float*)d_in[10];
  const float* W1  = (const float*)d_in[11];
  const float* b1  = (const float*)d_in[12];
  const float* W2  = (const float*)d_in[13];
  const float* b2  = (const float*)d_in[14];
  float* out = (float*)d_out;

  unsigned short* ws  = (unsigned short*)d_ws;
  unsigned short* wqT = ws;            // [512][512] f16, WqT[n][k]=Wq[k][n]
  unsigned short* wkB = ws + 262144;   // [512][512] f16, plain Wk
  unsigned short* wvT = ws + 524288;   // [512][512] f16, WvT[n][k]=Wv[k][n]
  unsigned short* w1T = ws + 786432;   // [256][512] f16, W1T[m][k]=W1[k][m]

  k_tr_f16<<<64, 256, 0, stream>>>(Wq, wqT, 512, 512);
  k_cvt4_f16<<<256, 256, 0, stream>>>(Wk, wkB, 65536);
  k_tr_f16<<<64, 256, 0, stream>>>(Wv, wvT, 512, 512);
  k_tr_f16<<<32, 256, 0, stream>>>(W1, w1T, 512, 256);
  trust_main<<<6250, 512, 0, stream>>>(h_i, evo, vi, vj, bq, bk, bv, ld, b1, W2, b2,
                                       wqT, wkB, wvT, w1T, out);
}

// Round 10
// 778.750 us; speedup vs baseline: 2.1282x; 2.1282x over previous
//
#include <hip/hip_runtime.h>
#include <hip/hip_fp16.h>

typedef _Float16 f16;
typedef _Float16 f16x8 __attribute__((ext_vector_type(8)));
typedef __fp16 fp16x2_raw __attribute__((ext_vector_type(2)));
typedef float f32x4 __attribute__((ext_vector_type(4)));

#define DD 512
#define BM 16     // entities per block (2 evo halves of 8)
#define WW 6
#define NH 8
#define EP 520    // padded LDS row stride (f16): rows offset +4 banks -> ~2-way conflicts

union F16x8 { f16x8 v; unsigned u[4]; uint2 u2[2]; };
union H2U { __half2 h; unsigned u; };
union U4H { uint4 q; __half2 h[4]; };

__device__ __forceinline__ unsigned pkrtz(float a, float b) {
  union { fp16x2_raw h; unsigned u; } c;
  c.h = __builtin_amdgcn_cvt_pkrtz(a, b);
  return c.u;
}
__device__ __forceinline__ unsigned short f2h(float x) {
  union { f16 h; unsigned short u; } c; c.h = (f16)x; return c.u;
}
#define SCHED_FENCE() __builtin_amdgcn_sched_barrier(0)

// ---- prep: gather Wq/Wv (512x512) into per-(head,ct,kst) A/B fragment-order, f16 ----
// dst[(((wv*4+ct)*16+kst)*64 + lane)*8 + j] = src[kst*32+(lane>>4)*8+j][wv*64+ct*16+(lane&15)]
__global__ void k_prep_qv(const float* __restrict__ src, unsigned short* __restrict__ dst) {
  int i = blockIdx.x * 256 + threadIdx.x;   // 65536 threads, 4 j each
  int j0 = (i & 1) * 4;
  int lane = (i >> 1) & 63;
  int kst = (i >> 7) & 15;
  int ct = (i >> 11) & 3;
  int wv = (i >> 13) & 7;
  int col = wv * 64 + ct * 16 + (lane & 15);
  int row = kst * 32 + (lane >> 4) * 8 + j0;
  ushort4 o;
  o.x = f2h(src[(size_t)(row + 0) * DD + col]);
  o.y = f2h(src[(size_t)(row + 1) * DD + col]);
  o.z = f2h(src[(size_t)(row + 2) * DD + col]);
  o.w = f2h(src[(size_t)(row + 3) * DD + col]);
  *(ushort4*)&dst[(size_t)(((wv * 4 + ct) * 16 + kst) * 64 + lane) * 8 + j0] = o;
}

// ---- prep: gather Wk into qk-A-frag order (sigma slot permutation baked in) ----
// dst[((((wv*16+ch)*2+kst)*2+ab)*64+lane)*8+j] = Wk[ch*32+ab*16+(lane&15)]
//                                                  [wv*64+kst*32+(j<4?0:16)+(lane>>4)*4+(j&3)]
__global__ void k_prep_wk(const float* __restrict__ src, unsigned short* __restrict__ dst) {
  int i = blockIdx.x * 256 + threadIdx.x;   // 65536 threads
  int j0 = (i & 1) * 4;
  int lane = (i >> 1) & 63;
  int ab = (i >> 7) & 1;
  int kst = (i >> 8) & 1;
  int ch = (i >> 9) & 15;
  int wv = (i >> 13) & 7;
  int row = ch * 32 + ab * 16 + (lane & 15);
  int cb = wv * 64 + kst * 32 + (j0 ? 16 : 0) + ((lane >> 4) & 3) * 4;
  float4 v = *(const float4*)&src[(size_t)row * DD + cb];
  ushort4 o; o.x = f2h(v.x); o.y = f2h(v.y); o.z = f2h(v.z); o.w = f2h(v.w);
  *(ushort4*)&dst[(size_t)((((wv * 16 + ch) * 2 + kst) * 2 + ab) * 64 + lane) * 8 + j0] = o;
}

// ---- prep: gather W1 (512x256) ----
__global__ void k_prep_w1(const float* __restrict__ src, unsigned short* __restrict__ dst) {
  int i = blockIdx.x * 256 + threadIdx.x;   // 32768 threads
  int j0 = (i & 1) * 4;
  int lane = (i >> 1) & 63;
  int kst = (i >> 7) & 15;
  int ct = (i >> 11) & 1;
  int wv = (i >> 12) & 7;
  int col = wv * 32 + ct * 16 + (lane & 15);
  int row = kst * 32 + (lane >> 4) * 8 + j0;
  ushort4 o;
  o.x = f2h(src[(size_t)(row + 0) * 256 + col]);
  o.y = f2h(src[(size_t)(row + 1) * 256 + col]);
  o.z = f2h(src[(size_t)(row + 2) * 256 + col]);
  o.w = f2h(src[(size_t)(row + 3) * 256 + col]);
  *(ushort4*)&dst[(size_t)(((wv * 2 + ct) * 16 + kst) * 64 + lane) * 8 + j0] = o;
}

// ---------- main: 16 entities/block, 8 waves = 8 heads, evo in 2 halves, f16 ----------
// launch_bounds 2nd arg = min BLOCKS/CU (CUDA semantics, r3 evidence) -> 128-reg cap.
// r9 lesson: latency-bound (all pipes <12%); weight loads were 16-line scatters. Now all
// weight loads are coalesced 1KB/instr from pre-permuted ws layouts; BM=16 halves traffic.
__global__ __launch_bounds__(512, 2) void trust_main(
    const float* __restrict__ h_i, const float* __restrict__ evo,
    const float* __restrict__ var_i, const float* __restrict__ var_j,
    const float* __restrict__ bq, const float* __restrict__ bk, const float* __restrict__ bv,
    const float* __restrict__ ld, const float* __restrict__ b1,
    const float* __restrict__ W2, const float* __restrict__ b2,
    const unsigned short* __restrict__ wqA, const unsigned short* __restrict__ wkA,
    const unsigned short* __restrict__ wvA, const unsigned short* __restrict__ w1A,
    float* __restrict__ out) {
  __shared__ unsigned short evo_s[48 * EP];   // 49920 B, one half (8 ents x 6 w)
  __shared__ unsigned short qh_s[16 * EP];    // 16640 B, h -> pooled (16 rows)
  __shared__ float score_s[NH * BM * WW];     // 3072 B
  __shared__ float logit_s[BM * NH];          // 512 B
  __shared__ float conf_s[BM];                // 64 B
  // total 70208 B -> 2 blocks/CU

  const int t = threadIdx.x;
  const int wv = t >> 6;       // wave == head
  const int l = t & 63;
  const int l16 = l & 15;
  const int lq = l >> 4;
  const int e0 = blockIdx.x * BM;

  // decay bias
  float biasw[WW];
  {
    float rd = expf(ld[0]);
    float dsum = 0.f;
    #pragma unroll
    for (int w6 = 0; w6 < WW; ++w6) { biasw[w6] = expf(rd * (float)w6); dsum += biasw[w6]; }
    float dinv = 1.f / dsum;
    #pragma unroll
    for (int w6 = 0; w6 < WW; ++w6) biasw[w6] *= dinv;
  }

  const float4* ev4 = (const float4*)evo + (size_t)e0 * (WW * DD / 4);

  // ---- P0: stage evo half0 (ents 0-7) + h (16 rows) to LDS f16; conf ----
  {
    #pragma unroll
    for (int i = 0; i < 12; ++i) {
      int idx = i * 512 + t;
      int row = idx >> 7, c4 = idx & 127;
      float4 v = ev4[idx];
      uint2 o; o.x = pkrtz(v.x, v.y); o.y = pkrtz(v.z, v.w);
      *(uint2*)&evo_s[row * EP + c4 * 4] = o;
      if ((i & 3) == 3) SCHED_FENCE();
    }
    const float4* h4 = (const float4*)h_i + (size_t)e0 * (DD / 4);
    #pragma unroll
    for (int i = 0; i < 4; ++i) {
      int idx = i * 512 + t;
      int row = idx >> 7, c4 = idx & 127;
      float4 v = h4[idx];
      uint2 o; o.x = pkrtz(v.x, v.y); o.y = pkrtz(v.z, v.w);
      *(uint2*)&qh_s[row * EP + c4 * 4] = o;
    }
    int ce = t >> 5, cs = t & 31;
    const float4* vi4 = (const float4*)var_i + (size_t)(e0 + ce) * (DD / 4);
    const float4* vj4 = (const float4*)var_j + (size_t)(e0 + ce) * (DD / 4);
    float si = 0.f, sj = 0.f;
    #pragma unroll
    for (int i = 0; i < 4; ++i) {
      float4 a = vi4[i * 32 + cs]; si += a.x + a.y + a.z + a.w;
      float4 b = vj4[i * 32 + cs]; sj += b.x + b.y + b.z + b.w;
    }
    #pragma unroll
    for (int m = 1; m <= 16; m <<= 1) { si += __shfl_xor(si, m); sj += __shfl_xor(sj, m); }
    if (cs == 0) {
      float ci = 1.f / (1.f + fmaxf(sqrtf(si * (1.f / DD)), 1e-6f));
      float cj = 1.f / (1.f + fmaxf(sqrtf(sj * (1.f / DD)), 1e-6f));
      conf_s[ce] = fmaxf(0.5f * (logf(ci) + logf(cj)), -5.0f);
    }
  }
  __syncthreads();   // B1
  SCHED_FENCE();

  // ---- P1: Q^T per head (D rows = head-col, cols = 16 entities); Q stays in regs ----
  F16x8 qfr[2];      // qk B-frags, sigma slot order
  float qb;          // Q[e].bk at lane l16=e
  {
    f32x4 qacc[4] = {};
    const unsigned short* wqp = wqA + (size_t)wv * 4 * 16 * 512 + l * 8;
    #pragma unroll
    for (int kst = 0; kst < 16; ++kst) {
      f16x8 hb = *reinterpret_cast<const f16x8*>(&qh_s[l16 * EP + kst * 32 + lq * 8]);
      #pragma unroll
      for (int ct = 0; ct < 4; ++ct) {
        f16x8 a = *reinterpret_cast<const f16x8*>(&wqp[(ct * 16 + kst) * 512]);
        qacc[ct] = __builtin_amdgcn_mfma_f32_16x16x32_f16(a, hb, qacc[ct], 0, 0, 0);
      }
      if (kst & 1) SCHED_FENCE();
    }
    qb = 0.f;
    #pragma unroll
    for (int ct = 0; ct < 4; ++ct) {
      float4 bq4 = *(const float4*)&bq[wv * 64 + ct * 16 + lq * 4];
      float4 bk4 = *(const float4*)&bk[wv * 64 + ct * 16 + lq * 4];
      float q0 = qacc[ct][0] + bq4.x, q1 = qacc[ct][1] + bq4.y;
      float q2 = qacc[ct][2] + bq4.z, q3 = qacc[ct][3] + bq4.w;
      qb += q0 * bk4.x + q1 * bk4.y + q2 * bk4.z + q3 * bk4.w;
      qfr[ct >> 1].u[(ct & 1) * 2]     = pkrtz(q0, q1);
      qfr[ct >> 1].u[(ct & 1) * 2 + 1] = pkrtz(q2, q3);
    }
    qb += __shfl_xor(qb, 16);
    qb += __shfl_xor(qb, 32);   // lane l16=e holds qb[e]
  }
  SCHED_FENCE();

  f32x4 pacc[4] = {};   // pooled accumulator (spans both halves)
  const unsigned short* wkp = wkA + (size_t)wv * 16 * 2 * 2 * 512 + l * 8;
  const unsigned short* wvp = wvA + (size_t)wv * 4 * 16 * 512 + l * 8;

  #pragma unroll
  for (int H = 0; H < 2; ++H) {
    if (H == 1) {
      __syncthreads();   // B2: all waves done reading evo half0
      const float4* ev4b = ev4 + 6144;
      #pragma unroll
      for (int i = 0; i < 12; ++i) {
        int idx = i * 512 + t;
        int row = idx >> 7, c4 = idx & 127;
        float4 v = ev4b[idx];
        uint2 o; o.x = pkrtz(v.x, v.y); o.y = pkrtz(v.z, v.w);
        *(uint2*)&evo_s[row * EP + c4 * 4] = o;
        if ((i & 3) == 3) SCHED_FENCE();
      }
      __syncthreads();   // B3
    }

    // ---- score: Qk chunk (coalesced wkA loads) -> af -> 3 evo MFMAs; recompute per half ----
    f32x4 sacc0 = {}, sacc1 = {}, sacc2 = {};
    #pragma unroll
    for (int ch = 0; ch < 16; ++ch) {
      f32x4 qk0 = {}, qk1 = {};
      #pragma unroll
      for (int kst = 0; kst < 2; ++kst) {
        f16x8 a0 = *reinterpret_cast<const f16x8*>(&wkp[((ch * 2 + kst) * 2 + 0) * 512]);
        f16x8 a1 = *reinterpret_cast<const f16x8*>(&wkp[((ch * 2 + kst) * 2 + 1) * 512]);
        qk0 = __builtin_amdgcn_mfma_f32_16x16x32_f16(a0, qfr[kst].v, qk0, 0, 0, 0);
        qk1 = __builtin_amdgcn_mfma_f32_16x16x32_f16(a1, qfr[kst].v, qk1, 0, 0, 0);
      }
      F16x8 af;
      af.u[0] = pkrtz(qk0[0], qk0[1]); af.u[1] = pkrtz(qk0[2], qk0[3]);
      af.u[2] = pkrtz(qk1[0], qk1[1]); af.u[3] = pkrtz(qk1[2], qk1[3]);
      int cb = ch * 32 + lq * 4;
      {
        F16x8 b; b.u2[0] = *(const uint2*)&evo_s[l16 * EP + cb];
        b.u2[1] = *(const uint2*)&evo_s[l16 * EP + cb + 16];
        sacc0 = __builtin_amdgcn_mfma_f32_16x16x32_f16(af.v, b.v, sacc0, 0, 0, 0);
      }
      {
        F16x8 b; b.u2[0] = *(const uint2*)&evo_s[(16 + l16) * EP + cb];
        b.u2[1] = *(const uint2*)&evo_s[(16 + l16) * EP + cb + 16];
        sacc1 = __builtin_amdgcn_mfma_f32_16x16x32_f16(af.v, b.v, sacc1, 0, 0, 0);
      }
      {
        F16x8 b; b.u2[0] = *(const uint2*)&evo_s[(32 + l16) * EP + cb];
        b.u2[1] = *(const uint2*)&evo_s[(32 + l16) * EP + cb + 16];
        sacc2 = __builtin_amdgcn_mfma_f32_16x16x32_f16(af.v, b.v, sacc2, 0, 0, 0);
      }
      if (ch & 1) SCHED_FENCE();
    }
    SCHED_FENCE();

    // extract S[e][w]: D rows = entities, cols l16 -> half-local evo row L = 6*eL + w
    #pragma unroll
    for (int r = 0; r < 4; ++r) {
      int e = lq * 4 + r, eL = e - 8 * H;
      { int w = l16 - 6 * eL;      if (w >= 0 && w < WW) score_s[wv * 96 + e * 6 + w] = sacc0[r]; }
      { int w = 16 + l16 - 6 * eL; if (w >= 0 && w < WW) score_s[wv * 96 + e * 6 + w] = sacc1[r]; }
      { int w = 32 + l16 - 6 * eL; if (w >= 0 && w < WW) score_s[wv * 96 + e * 6 + w] = sacc2[r]; }
    }
    // softmax for this half's entities (attn written back by l16==0 lanes)
    #pragma unroll
    for (int r = 0; r < 4; ++r) {
      int e = lq * 4 + r, eL = e - 8 * H;
      if (eL >= 0 && eL < 8) {
        float qbv = __shfl(qb, e);
        float sc[WW]; float mx = -1e30f;
        #pragma unroll
        for (int w6 = 0; w6 < WW; ++w6) {
          sc[w6] = 0.125f * (score_s[wv * 96 + e * 6 + w6] + qbv) + biasw[w6];
          mx = fmaxf(mx, sc[w6]);
        }
        float ssum = 0.f;
        #pragma unroll
        for (int w6 = 0; w6 < WW; ++w6) { sc[w6] = expf(sc[w6] - mx); ssum += sc[w6]; }
        float sinv = 1.f / ssum;
        if (l16 == 0) {
          #pragma unroll
          for (int w6 = 0; w6 < WW; ++w6) score_s[wv * 96 + e * 6 + w6] = sc[w6] * sinv;
        }
      }
    }
    SCHED_FENCE();

    // ---- agg via hfma2 (lane = entity l16; other-half lanes get exact 0) ----
    {
      __half2 aw2[WW];
      bool inh = ((l16 >> 3) == H);
      #pragma unroll
      for (int w6 = 0; w6 < WW; ++w6) {
        float v = score_s[wv * 96 + l16 * 6 + w6];
        v = inh ? v : 0.f;
        H2U a; a.u = pkrtz(v, v); aw2[w6] = a.h;
      }
      const int arow = (l16 & 7) * 6;
      #pragma unroll
      for (int ch = 0; ch < 16; ++ch) {
        H2U z; z.u = 0;
        __half2 ac0 = z.h, ac1 = z.h, ac2 = z.h, ac3 = z.h;
        #pragma unroll
        for (int w6 = 0; w6 < WW; ++w6) {
          U4H vv; vv.q = *(const uint4*)&evo_s[(arow + w6) * EP + ch * 32 + lq * 8];
          ac0 = __hfma2(vv.h[0], aw2[w6], ac0);
          ac1 = __hfma2(vv.h[1], aw2[w6], ac1);
          ac2 = __hfma2(vv.h[2], aw2[w6], ac2);
          ac3 = __hfma2(vv.h[3], aw2[w6], ac3);
        }
        F16x8 af;
        { H2U c; c.h = ac0; af.u[0] = c.u; c.h = ac1; af.u[1] = c.u;
          c.h = ac2; af.u[2] = c.u; c.h = ac3; af.u[3] = c.u; }
        #pragma unroll
        for (int ct = 0; ct < 4; ++ct) {
          f16x8 b = *reinterpret_cast<const f16x8*>(&wvp[(ct * 16 + ch) * 512]);
          pacc[ct] = __builtin_amdgcn_mfma_f32_16x16x32_f16(af.v, b, pacc[ct], 0, 0, 0);
        }
        SCHED_FENCE();
      }
    }
  }

  // pooled -> qh_s (f16); all waves' P1/Qk qh-reads finished before H1 barriers
  #pragma unroll
  for (int ct = 0; ct < 4; ++ct) {
    int col = wv * 64 + ct * 16 + l16;
    float bvv = bv[col];
    #pragma unroll
    for (int r = 0; r < 4; ++r)
      qh_s[(lq * 4 + r) * EP + col] = f2h(pacc[ct][r] + bvv);
  }
  __syncthreads();   // B4

  // ---- P6: hmid = gelu(pooled @ W1 + b1); logit partials ----
  {
    f32x4 hacc[2] = {};
    const unsigned short* w1p = w1A + (size_t)wv * 2 * 16 * 512 + l * 8;
    #pragma unroll
    for (int kst = 0; kst < 16; ++kst) {
      f16x8 a = *reinterpret_cast<const f16x8*>(&qh_s[l16 * EP + kst * 32 + lq * 8]);
      #pragma unroll
      for (int ct = 0; ct < 2; ++ct) {
        f16x8 b = *reinterpret_cast<const f16x8*>(&w1p[(ct * 16 + kst) * 512]);
        hacc[ct] = __builtin_amdgcn_mfma_f32_16x16x32_f16(a, b, hacc[ct], 0, 0, 0);
      }
      if (kst & 1) SCHED_FENCE();
    }
    float lg[4] = {0.f, 0.f, 0.f, 0.f};
    #pragma unroll
    for (int ct = 0; ct < 2; ++ct) {
      int m = wv * 32 + ct * 16 + l16;
      float b1v = b1[m], w2v = W2[m];
      #pragma unroll
      for (int r = 0; r < 4; ++r) {
        float x = hacc[ct][r] + b1v;
        float g = 0.5f * x * (1.f + erff(x * 0.70710678118f));
        lg[r] += g * w2v;
      }
    }
    #pragma unroll
    for (int r = 0; r < 4; ++r) {
      #pragma unroll
      for (int m = 1; m <= 8; m <<= 1) lg[r] += __shfl_xor(lg[r], m);
    }
    if (l16 == 0) {
      #pragma unroll
      for (int r = 0; r < 4; ++r) logit_s[(lq * 4 + r) * NH + wv] = lg[r];
    }
  }
  __syncthreads();   // B5

  // ---- P7: combine + sigmoid ----
  if (t < BM) {
    float s = 0.f;
    #pragma unroll
    for (int w8 = 0; w8 < NH; ++w8) s += logit_s[t * NH + w8];
    s += b2[0] + conf_s[t];
    out[e0 + t] = 1.f / (1.f + expf(-s));
  }
}

extern "C" void kernel_launch(void* const* d_in, const int* in_sizes, int n_in,
                              void* d_out, int out_size, void* d_ws, size_t ws_size,
                              hipStream_t stream) {
  (void)in_sizes; (void)n_in; (void)out_size; (void)ws_size;
  const float* h_i = (const float*)d_in[0];
  const float* evo = (const float*)d_in[1];
  const float* vi  = (const float*)d_in[2];
  const float* vj  = (const float*)d_in[3];
  const float* Wq  = (const float*)d_in[4];
  const float* bq  = (const float*)d_in[5];
  const float* Wk  = (const float*)d_in[6];
  const float* bk  = (const float*)d_in[7];
  const float* Wv  = (const float*)d_in[8];
  const float* bv  = (const float*)d_in[9];
  const float* ld  = (const float*)d_in[10];
  const float* W1  = (const float*)d_in[11];
  const float* b1  = (const float*)d_in[12];
  const float* W2  = (const float*)d_in[13];
  const float* b2  = (const float*)d_in[14];
  float* out = (float*)d_out;

  unsigned short* ws  = (unsigned short*)d_ws;
  unsigned short* wqA = ws;            // 512KB f16, Wq fragment-order
  unsigned short* wkA = ws + 262144;   // 512KB f16, Wk qk-A-frag order
  unsigned short* wvA = ws + 524288;   // 512KB f16, Wv B-frag order
  unsigned short* w1A = ws + 786432;   // 256KB f16, W1 B-frag order

  k_prep_qv<<<256, 256, 0, stream>>>(Wq, wqA);
  k_prep_wk<<<256, 256, 0, stream>>>(Wk, wkA);
  k_prep_qv<<<256, 256, 0, stream>>>(Wv, wvA);
  k_prep_w1<<<128, 256, 0, stream>>>(W1, w1A);
  trust_main<<<3125, 512, 0, stream>>>(h_i, evo, vi, vj, bq, bk, bv, ld, b1, W2, b2,
                                       wqA, wkA, wvA, w1A, out);
}

// Round 11
// 498.907 us; speedup vs baseline: 3.3219x; 1.5609x over previous
//
#include <hip/hip_runtime.h>
#include <hip/hip_fp16.h>

typedef _Float16 f16;
typedef _Float16 f16x8 __attribute__((ext_vector_type(8)));
typedef __fp16 fp16x2_raw __attribute__((ext_vector_type(2)));
typedef float f32x4 __attribute__((ext_vector_type(4)));

#define DD 512
#define BM 16     // entities per block (2 evo halves of 8)
#define WW 6
#define NH 8
#define EP 520    // padded LDS row stride (f16): rows offset +4 banks -> ~2-way conflicts

union F16x8 { f16x8 v; unsigned u[4]; uint2 u2[2]; };
union H2U { __half2 h; unsigned u; };
union U4H { uint4 q; __half2 h[4]; };

__device__ __forceinline__ unsigned pkrtz(float a, float b) {
  union { fp16x2_raw h; unsigned u; } c;
  c.h = __builtin_amdgcn_cvt_pkrtz(a, b);
  return c.u;
}
__device__ __forceinline__ unsigned short f2h(float x) {
  union { f16 h; unsigned short u; } c; c.h = (f16)x; return c.u;
}
#define SCHED_FENCE() __builtin_amdgcn_sched_barrier(0)

// ---- prep: gather Wq/Wv (512x512) into per-(head,ct,kst) A/B fragment-order, f16 ----
__global__ void k_prep_qv(const float* __restrict__ src, unsigned short* __restrict__ dst) {
  int i = blockIdx.x * 256 + threadIdx.x;   // 65536 threads, 4 j each
  int j0 = (i & 1) * 4;
  int lane = (i >> 1) & 63;
  int kst = (i >> 7) & 15;
  int ct = (i >> 11) & 3;
  int wv = (i >> 13) & 7;
  int col = wv * 64 + ct * 16 + (lane & 15);
  int row = kst * 32 + (lane >> 4) * 8 + j0;
  ushort4 o;
  o.x = f2h(src[(size_t)(row + 0) * DD + col]);
  o.y = f2h(src[(size_t)(row + 1) * DD + col]);
  o.z = f2h(src[(size_t)(row + 2) * DD + col]);
  o.w = f2h(src[(size_t)(row + 3) * DD + col]);
  *(ushort4*)&dst[(size_t)(((wv * 4 + ct) * 16 + kst) * 64 + lane) * 8 + j0] = o;
}

// ---- prep: gather Wk into qk-A-frag order (sigma slot permutation baked in) ----
__global__ void k_prep_wk(const float* __restrict__ src, unsigned short* __restrict__ dst) {
  int i = blockIdx.x * 256 + threadIdx.x;   // 65536 threads
  int j0 = (i & 1) * 4;
  int lane = (i >> 1) & 63;
  int ab = (i >> 7) & 1;
  int kst = (i >> 8) & 1;
  int ch = (i >> 9) & 15;
  int wv = (i >> 13) & 7;
  int row = ch * 32 + ab * 16 + (lane & 15);
  int cb = wv * 64 + kst * 32 + (j0 ? 16 : 0) + ((lane >> 4) & 3) * 4;
  float4 v = *(const float4*)&src[(size_t)row * DD + cb];
  ushort4 o; o.x = f2h(v.x); o.y = f2h(v.y); o.z = f2h(v.z); o.w = f2h(v.w);
  *(ushort4*)&dst[(size_t)((((wv * 16 + ch) * 2 + kst) * 2 + ab) * 64 + lane) * 8 + j0] = o;
}

// ---- prep: gather W1 (512x256) ----
__global__ void k_prep_w1(const float* __restrict__ src, unsigned short* __restrict__ dst) {
  int i = blockIdx.x * 256 + threadIdx.x;   // 32768 threads
  int j0 = (i & 1) * 4;
  int lane = (i >> 1) & 63;
  int kst = (i >> 7) & 15;
  int ct = (i >> 11) & 1;
  int wv = (i >> 12) & 7;
  int col = wv * 32 + ct * 16 + (lane & 15);
  int row = kst * 32 + (lane >> 4) * 8 + j0;
  ushort4 o;
  o.x = f2h(src[(size_t)(row + 0) * 256 + col]);
  o.y = f2h(src[(size_t)(row + 1) * 256 + col]);
  o.z = f2h(src[(size_t)(row + 2) * 256 + col]);
  o.w = f2h(src[(size_t)(row + 3) * 256 + col]);
  *(ushort4*)&dst[(size_t)(((wv * 2 + ct) * 16 + kst) * 64 + lane) * 8 + j0] = o;
}

// ---------- main: 16 entities/block, 8 waves = 8 heads, evo in 2 halves, f16 ----------
// launch_bounds(512,4): min 4 BLOCKS/CU (CUDA semantics, r3) -> 64 arch-VGPR cap; accs go
// to AGPRs (r7-proven with unroll<=2). LDS 70.6KB actually limits residency to 2 blocks/CU
// = 16 waves (vs 8 at VGPR 128, r10) -> double latency hiding. Weight loads stay coalesced.
__global__ __launch_bounds__(512, 4) void trust_main(
    const float* __restrict__ h_i, const float* __restrict__ evo,
    const float* __restrict__ var_i, const float* __restrict__ var_j,
    const float* __restrict__ bq, const float* __restrict__ bk, const float* __restrict__ bv,
    const float* __restrict__ ld, const float* __restrict__ b1,
    const float* __restrict__ W2, const float* __restrict__ b2,
    const unsigned short* __restrict__ wqA, const unsigned short* __restrict__ wkA,
    const unsigned short* __restrict__ wvA, const unsigned short* __restrict__ w1A,
    float* __restrict__ out) {
  __shared__ unsigned short evo_s[48 * EP];   // 49920 B, one half (8 ents x 6 w)
  __shared__ unsigned short qh_s[16 * EP];    // 16640 B, h -> pooled (16 rows)
  __shared__ float score_s[NH * BM * WW];     // 3072 B
  __shared__ float logit_s[BM * NH];          // 512 B
  __shared__ float conf_s[BM];                // 64 B
  // total 70208 B -> 2 blocks/CU

  const int t = threadIdx.x;
  const int wv = t >> 6;       // wave == head
  const int l = t & 63;
  const int l16 = l & 15;
  const int lq = l >> 4;
  const int e0 = blockIdx.x * BM;

  // decay bias
  float biasw[WW];
  {
    float rd = expf(ld[0]);
    float dsum = 0.f;
    #pragma unroll
    for (int w6 = 0; w6 < WW; ++w6) { biasw[w6] = expf(rd * (float)w6); dsum += biasw[w6]; }
    float dinv = 1.f / dsum;
    #pragma unroll
    for (int w6 = 0; w6 < WW; ++w6) biasw[w6] *= dinv;
  }

  const float4* ev4 = (const float4*)evo + (size_t)e0 * (WW * DD / 4);

  // ---- P0: stage evo half0 (ents 0-7) + h (16 rows) to LDS f16; conf ----
  {
    #pragma unroll 4
    for (int i = 0; i < 12; ++i) {
      int idx = i * 512 + t;
      int row = idx >> 7, c4 = idx & 127;
      float4 v = ev4[idx];
      uint2 o; o.x = pkrtz(v.x, v.y); o.y = pkrtz(v.z, v.w);
      *(uint2*)&evo_s[row * EP + c4 * 4] = o;
    }
    const float4* h4 = (const float4*)h_i + (size_t)e0 * (DD / 4);
    #pragma unroll
    for (int i = 0; i < 4; ++i) {
      int idx = i * 512 + t;
      int row = idx >> 7, c4 = idx & 127;
      float4 v = h4[idx];
      uint2 o; o.x = pkrtz(v.x, v.y); o.y = pkrtz(v.z, v.w);
      *(uint2*)&qh_s[row * EP + c4 * 4] = o;
    }
    int ce = t >> 5, cs = t & 31;
    const float4* vi4 = (const float4*)var_i + (size_t)(e0 + ce) * (DD / 4);
    const float4* vj4 = (const float4*)var_j + (size_t)(e0 + ce) * (DD / 4);
    float si = 0.f, sj = 0.f;
    #pragma unroll
    for (int i = 0; i < 4; ++i) {
      float4 a = vi4[i * 32 + cs]; si += a.x + a.y + a.z + a.w;
      float4 b = vj4[i * 32 + cs]; sj += b.x + b.y + b.z + b.w;
    }
    #pragma unroll
    for (int m = 1; m <= 16; m <<= 1) { si += __shfl_xor(si, m); sj += __shfl_xor(sj, m); }
    if (cs == 0) {
      float ci = 1.f / (1.f + fmaxf(sqrtf(si * (1.f / DD)), 1e-6f));
      float cj = 1.f / (1.f + fmaxf(sqrtf(sj * (1.f / DD)), 1e-6f));
      conf_s[ce] = fmaxf(0.5f * (logf(ci) + logf(cj)), -5.0f);
    }
  }
  __syncthreads();   // B1
  SCHED_FENCE();

  // ---- P1: Q^T per head (D rows = head-col, cols = 16 entities); Q stays in regs ----
  F16x8 qfr[2];      // qk B-frags, sigma slot order
  float qb;          // Q[e].bk at lane l16=e
  {
    f32x4 qacc[4] = {};
    const unsigned short* wqp = wqA + (size_t)wv * 4 * 16 * 512 + l * 8;
    #pragma unroll 2
    for (int kst = 0; kst < 16; ++kst) {
      f16x8 hb = *reinterpret_cast<const f16x8*>(&qh_s[l16 * EP + kst * 32 + lq * 8]);
      #pragma unroll
      for (int ct = 0; ct < 4; ++ct) {
        f16x8 a = *reinterpret_cast<const f16x8*>(&wqp[(ct * 16 + kst) * 512]);
        qacc[ct] = __builtin_amdgcn_mfma_f32_16x16x32_f16(a, hb, qacc[ct], 0, 0, 0);
      }
    }
    qb = 0.f;
    #pragma unroll
    for (int ct = 0; ct < 4; ++ct) {
      float4 bq4 = *(const float4*)&bq[wv * 64 + ct * 16 + lq * 4];
      float4 bk4 = *(const float4*)&bk[wv * 64 + ct * 16 + lq * 4];
      float q0 = qacc[ct][0] + bq4.x, q1 = qacc[ct][1] + bq4.y;
      float q2 = qacc[ct][2] + bq4.z, q3 = qacc[ct][3] + bq4.w;
      qb += q0 * bk4.x + q1 * bk4.y + q2 * bk4.z + q3 * bk4.w;
      qfr[ct >> 1].u[(ct & 1) * 2]     = pkrtz(q0, q1);
      qfr[ct >> 1].u[(ct & 1) * 2 + 1] = pkrtz(q2, q3);
    }
    qb += __shfl_xor(qb, 16);
    qb += __shfl_xor(qb, 32);   // lane l16=e holds qb[e]
  }
  SCHED_FENCE();

  f32x4 pacc[4] = {};   // pooled accumulator (spans both halves)
  const unsigned short* wkp = wkA + (size_t)wv * 16 * 2 * 2 * 512 + l * 8;
  const unsigned short* wvp = wvA + (size_t)wv * 4 * 16 * 512 + l * 8;

  #pragma unroll
  for (int H = 0; H < 2; ++H) {
    if (H == 1) {
      __syncthreads();   // B2: all waves done reading evo half0
      const float4* ev4b = ev4 + 6144;
      #pragma unroll 4
      for (int i = 0; i < 12; ++i) {
        int idx = i * 512 + t;
        int row = idx >> 7, c4 = idx & 127;
        float4 v = ev4b[idx];
        uint2 o; o.x = pkrtz(v.x, v.y); o.y = pkrtz(v.z, v.w);
        *(uint2*)&evo_s[row * EP + c4 * 4] = o;
      }
      __syncthreads();   // B3
    }

    // ---- score: Qk chunk (coalesced wkA loads) -> af -> 3 evo MFMAs; recompute per half ----
    f32x4 sacc0 = {}, sacc1 = {}, sacc2 = {};
    #pragma unroll 1
    for (int ch = 0; ch < 16; ++ch) {
      f32x4 qk0 = {}, qk1 = {};
      #pragma unroll
      for (int kst = 0; kst < 2; ++kst) {
        f16x8 a0 = *reinterpret_cast<const f16x8*>(&wkp[((ch * 2 + kst) * 2 + 0) * 512]);
        f16x8 a1 = *reinterpret_cast<const f16x8*>(&wkp[((ch * 2 + kst) * 2 + 1) * 512]);
        qk0 = __builtin_amdgcn_mfma_f32_16x16x32_f16(a0, qfr[kst].v, qk0, 0, 0, 0);
        qk1 = __builtin_amdgcn_mfma_f32_16x16x32_f16(a1, qfr[kst].v, qk1, 0, 0, 0);
      }
      F16x8 af;
      af.u[0] = pkrtz(qk0[0], qk0[1]); af.u[1] = pkrtz(qk0[2], qk0[3]);
      af.u[2] = pkrtz(qk1[0], qk1[1]); af.u[3] = pkrtz(qk1[2], qk1[3]);
      int cb = ch * 32 + lq * 4;
      {
        F16x8 b; b.u2[0] = *(const uint2*)&evo_s[l16 * EP + cb];
        b.u2[1] = *(const uint2*)&evo_s[l16 * EP + cb + 16];
        sacc0 = __builtin_amdgcn_mfma_f32_16x16x32_f16(af.v, b.v, sacc0, 0, 0, 0);
      }
      {
        F16x8 b; b.u2[0] = *(const uint2*)&evo_s[(16 + l16) * EP + cb];
        b.u2[1] = *(const uint2*)&evo_s[(16 + l16) * EP + cb + 16];
        sacc1 = __builtin_amdgcn_mfma_f32_16x16x32_f16(af.v, b.v, sacc1, 0, 0, 0);
      }
      {
        F16x8 b; b.u2[0] = *(const uint2*)&evo_s[(32 + l16) * EP + cb];
        b.u2[1] = *(const uint2*)&evo_s[(32 + l16) * EP + cb + 16];
        sacc2 = __builtin_amdgcn_mfma_f32_16x16x32_f16(af.v, b.v, sacc2, 0, 0, 0);
      }
      if (ch & 1) SCHED_FENCE();
    }
    SCHED_FENCE();

    // extract S[e][w]: D rows = entities, cols l16 -> half-local evo row L = 6*eL + w
    #pragma unroll
    for (int r = 0; r < 4; ++r) {
      int e = lq * 4 + r, eL = e - 8 * H;
      { int w = l16 - 6 * eL;      if (w >= 0 && w < WW) score_s[wv * 96 + e * 6 + w] = sacc0[r]; }
      { int w = 16 + l16 - 6 * eL; if (w >= 0 && w < WW) score_s[wv * 96 + e * 6 + w] = sacc1[r]; }
      { int w = 32 + l16 - 6 * eL; if (w >= 0 && w < WW) score_s[wv * 96 + e * 6 + w] = sacc2[r]; }
    }
    // softmax for this half's entities (attn written back by l16==0 lanes)
    #pragma unroll
    for (int r = 0; r < 4; ++r) {
      int e = lq * 4 + r, eL = e - 8 * H;
      if (eL >= 0 && eL < 8) {
        float qbv = __shfl(qb, e);
        float sc[WW]; float mx = -1e30f;
        #pragma unroll
        for (int w6 = 0; w6 < WW; ++w6) {
          sc[w6] = 0.125f * (score_s[wv * 96 + e * 6 + w6] + qbv) + biasw[w6];
          mx = fmaxf(mx, sc[w6]);
        }
        float ssum = 0.f;
        #pragma unroll
        for (int w6 = 0; w6 < WW; ++w6) { sc[w6] = expf(sc[w6] - mx); ssum += sc[w6]; }
        float sinv = 1.f / ssum;
        if (l16 == 0) {
          #pragma unroll
          for (int w6 = 0; w6 < WW; ++w6) score_s[wv * 96 + e * 6 + w6] = sc[w6] * sinv;
        }
      }
    }
    SCHED_FENCE();

    // ---- agg via hfma2 (lane = entity l16; other-half lanes get exact 0) ----
    {
      __half2 aw2[WW];
      bool inh = ((l16 >> 3) == H);
      #pragma unroll
      for (int w6 = 0; w6 < WW; ++w6) {
        float v = score_s[wv * 96 + l16 * 6 + w6];
        v = inh ? v : 0.f;
        H2U a; a.u = pkrtz(v, v); aw2[w6] = a.h;
      }
      const int arow = (l16 & 7) * 6;
      #pragma unroll 1
      for (int ch = 0; ch < 16; ++ch) {
        H2U z; z.u = 0;
        __half2 ac0 = z.h, ac1 = z.h, ac2 = z.h, ac3 = z.h;
        #pragma unroll
        for (int w6 = 0; w6 < WW; ++w6) {
          U4H vv; vv.q = *(const uint4*)&evo_s[(arow + w6) * EP + ch * 32 + lq * 8];
          ac0 = __hfma2(vv.h[0], aw2[w6], ac0);
          ac1 = __hfma2(vv.h[1], aw2[w6], ac1);
          ac2 = __hfma2(vv.h[2], aw2[w6], ac2);
          ac3 = __hfma2(vv.h[3], aw2[w6], ac3);
        }
        F16x8 af;
        { H2U c; c.h = ac0; af.u[0] = c.u; c.h = ac1; af.u[1] = c.u;
          c.h = ac2; af.u[2] = c.u; c.h = ac3; af.u[3] = c.u; }
        #pragma unroll
        for (int ct = 0; ct < 4; ++ct) {
          f16x8 b = *reinterpret_cast<const f16x8*>(&wvp[(ct * 16 + ch) * 512]);
          pacc[ct] = __builtin_amdgcn_mfma_f32_16x16x32_f16(af.v, b, pacc[ct], 0, 0, 0);
        }
        if (ch & 1) SCHED_FENCE();
      }
    }
  }

  // pooled -> qh_s (f16)
  #pragma unroll
  for (int ct = 0; ct < 4; ++ct) {
    int col = wv * 64 + ct * 16 + l16;
    float bvv = bv[col];
    #pragma unroll
    for (int r = 0; r < 4; ++r)
      qh_s[(lq * 4 + r) * EP + col] = f2h(pacc[ct][r] + bvv);
  }
  __syncthreads();   // B4

  // ---- P6: hmid = gelu(pooled @ W1 + b1); logit partials ----
  {
    f32x4 hacc[2] = {};
    const unsigned short* w1p = w1A + (size_t)wv * 2 * 16 * 512 + l * 8;
    #pragma unroll 2
    for (int kst = 0; kst < 16; ++kst) {
      f16x8 a = *reinterpret_cast<const f16x8*>(&qh_s[l16 * EP + kst * 32 + lq * 8]);
      #pragma unroll
      for (int ct = 0; ct < 2; ++ct) {
        f16x8 b = *reinterpret_cast<const f16x8*>(&w1p[(ct * 16 + kst) * 512]);
        hacc[ct] = __builtin_amdgcn_mfma_f32_16x16x32_f16(a, b, hacc[ct], 0, 0, 0);
      }
    }
    float lg[4] = {0.f, 0.f, 0.f, 0.f};
    #pragma unroll
    for (int ct = 0; ct < 2; ++ct) {
      int m = wv * 32 + ct * 16 + l16;
      float b1v = b1[m], w2v = W2[m];
      #pragma unroll
      for (int r = 0; r < 4; ++r) {
        float x = hacc[ct][r] + b1v;
        float g = 0.5f * x * (1.f + erff(x * 0.70710678118f));
        lg[r] += g * w2v;
      }
    }
    #pragma unroll
    for (int r = 0; r < 4; ++r) {
      #pragma unroll
      for (int m = 1; m <= 8; m <<= 1) lg[r] += __shfl_xor(lg[r], m);
    }
    if (l16 == 0) {
      #pragma unroll
      for (int r = 0; r < 4; ++r) logit_s[(lq * 4 + r) * NH + wv] = lg[r];
    }
  }
  __syncthreads();   // B5

  // ---- P7: combine + sigmoid ----
  if (t < BM) {
    float s = 0.f;
    #pragma unroll
    for (int w8 = 0; w8 < NH; ++w8) s += logit_s[t * NH + w8];
    s += b2[0] + conf_s[t];
    out[e0 + t] = 1.f / (1.f + expf(-s));
  }
}

extern "C" void kernel_launch(void* const* d_in, const int* in_sizes, int n_in,
                              void* d_out, int out_size, void* d_ws, size_t ws_size,
                              hipStream_t stream) {
  (void)in_sizes; (void)n_in; (void)out_size; (void)ws_size;
  const float* h_i = (const float*)d_in[0];
  const float* evo = (const float*)d_in[1];
  const float* vi  = (const float*)d_in[2];
  const float* vj  = (const float*)d_in[3];
  const float* Wq  = (const float*)d_in[4];
  const float* bq  = (const float*)d_in[5];
  const float* Wk  = (const float*)d_in[6];
  const float* bk  = (const float*)d_in[7];
  const float* Wv  = (const float*)d_in[8];
  const float* bv  = (const float*)d_in[9];
  const float* ld  = (const float*)d_in[10];
  const float* W1  = (const float*)d_in[11];
  const float* b1  = (const float*)d_in[12];
  const float* W2  = (const float*)d_in[13];
  const float* b2  = (const float*)d_in[14];
  float* out = (float*)d_out;

  unsigned short* ws  = (unsigned short*)d_ws;
  unsigned short* wqA = ws;            // 512KB f16, Wq fragment-order
  unsigned short* wkA = ws + 262144;   // 512KB f16, Wk qk-A-frag order
  unsigned short* wvA = ws + 524288;   // 512KB f16, Wv B-frag order
  unsigned short* w1A = ws + 786432;   // 256KB f16, W1 B-frag order

  k_prep_qv<<<256, 256, 0, stream>>>(Wq, wqA);
  k_prep_wk<<<256, 256, 0, stream>>>(Wk, wkA);
  k_prep_qv<<<256, 256, 0, stream>>>(Wv, wvA);
  k_prep_w1<<<128, 256, 0, stream>>>(W1, w1A);
  trust_main<<<3125, 512, 0, stream>>>(h_i, evo, vi, vj, bq, bk, bv, ld, b1, W2, b2,
                                       wqA, wkA, wvA, w1A, out);
}